// Round 5
// baseline (3085.149 us; speedup 1.0000x reference)
//
#include <hip/hip_runtime.h>
#include <math.h>
#include <stdint.h>

// ---------------------------------------------------------------------------
// BitResidualBlock via bf16-split MFMA.
// R5: (a) double-buffered X staging with ONE barrier per cc iteration
//     (global->reg prefetch at loop top, ds_write after MFMA body);
//     (b) plane-store epilogue transposed through LDS so global stores are
//     32B-contiguous (R3/R4's scattered 8B stores cost ~30us/conv).
// Wave tile 8m x 2n (128co x 32t), block 128co x 128t, 1024 blocks.
// ---------------------------------------------------------------------------

constexpr int B_ = 8, C_ = 512, T_ = 4096, K_ = 3;
constexpr int WELEM = C_ * C_ * K_;  // 786432 per tensor

typedef __bf16 bf16x8 __attribute__((ext_vector_type(8)));
typedef float f32x4 __attribute__((ext_vector_type(4)));
typedef unsigned short u16x8 __attribute__((ext_vector_type(8)));

// ws byte offsets
constexpr size_t OFF_PART = 0;
constexpr size_t OFF_S = 4096;
constexpr size_t OFF_AE = 8192;
constexpr size_t OFF_IB = 16384;
constexpr size_t OFF_WQ1 = 32768;  // ushort[3*WELEM], frag-swizzled
constexpr size_t OFF_WQ2 = OFF_WQ1 + (size_t)3 * WELEM * 2;
constexpr size_t NBCT = (size_t)B_ * C_ * T_;
constexpr size_t OFF_PHI = OFF_WQ2 + (size_t)3 * WELEM * 2;  // bf16 planes
constexpr size_t OFF_PLO = OFF_PHI + NBCT * 2;
constexpr size_t OFF_QHI = OFF_PLO + NBCT * 2;
constexpr size_t OFF_QLO = OFF_QHI + NBCT * 2;

__device__ inline unsigned short bf16_rne(float v) {
  unsigned int u = __builtin_bit_cast(unsigned int, v);
  unsigned int r = u + 0x7FFFu + ((u >> 16) & 1u);
  return (unsigned short)(r >> 16);
}

// --------------------------- absmean (deterministic) ------------------------
__global__ __launch_bounds__(256)
void absmean_partial(const float* __restrict__ w1, const float* __restrict__ w2,
                     float* __restrict__ part) {
  __shared__ float red[256];
  const int t = blockIdx.y;
  const float* src = (t < 3) ? (w1 + (size_t)t * WELEM) : (w2 + (size_t)(t - 3) * WELEM);
  const int base = blockIdx.x * (256 * 32);
  float v = 0.f;
#pragma unroll
  for (int j = 0; j < 32; ++j) v += fabsf(src[base + j * 256 + threadIdx.x]);
  red[threadIdx.x] = v;
  __syncthreads();
  for (int s = 128; s > 0; s >>= 1) {
    if (threadIdx.x < (unsigned)s) red[threadIdx.x] += red[threadIdx.x + s];
    __syncthreads();
  }
  if (threadIdx.x == 0) part[t * 96 + blockIdx.x] = red[0];
}

__global__ __launch_bounds__(128)
void absmean_final(const float* __restrict__ part, float* __restrict__ svec) {
  __shared__ float red[128];
  const int t = blockIdx.x;
  red[threadIdx.x] = (threadIdx.x < 96) ? part[t * 96 + threadIdx.x] : 0.f;
  __syncthreads();
  for (int s = 64; s > 0; s >>= 1) {
    if (threadIdx.x < (unsigned)s) red[threadIdx.x] += red[threadIdx.x + s];
    __syncthreads();
  }
  if (threadIdx.x == 0) svec[t] = red[0] / (float)WELEM;
}

// --------------------------- quantize -> ternary bf16, frag-swizzled --------
// dst layout: idx = (((st*16 + cc)*3 + tap)*32 + cot)*512 + lane*8 + j
//   where co = cot*16 + (lane&15), ci = cc*32 + (lane>>4)*8 + j.
__global__ __launch_bounds__(256)
void quantize_kernel(const float* __restrict__ src, unsigned short* __restrict__ dst,
                     const float* __restrict__ svec, int sbase) {
  const int idx = blockIdx.x * 256 + threadIdx.x;  // exact grid over 3*WELEM
  const int j = idx & 7;
  const int lane = (idx >> 3) & 63;
  const int cot = (idx >> 9) & 31;
  const int rest = idx >> 14;
  const int tap = rest % 3;
  const int rest2 = rest / 3;
  const int cc = rest2 & 15;
  const int st = rest2 >> 4;
  const int co = cot * 16 + (lane & 15);
  const int ci = cc * 32 + (lane >> 4) * 8 + j;
  const float s = svec[sbase + st];
  const float w = src[(((size_t)st * C_ + co) * C_ + ci) * K_ + tap];
  float q = rintf(w / (s + 1e-5f));
  q = fminf(1.f, fmaxf(-1.f, q));
  dst[idx] = (unsigned short)(__builtin_bit_cast(unsigned int, q) >> 16);
}

__global__ __launch_bounds__(256)
void snake_params_kernel(const float* __restrict__ al, const float* __restrict__ be,
                         float* __restrict__ ae, float* __restrict__ ib) {
  const int idx = blockIdx.x * 256 + threadIdx.x;
  if (idx < 3 * C_) {
    ae[idx] = expf(al[idx]);
    ib[idx] = 1.f / (expf(be[idx]) + 1e-9f);
  }
}

// --------------------------- transpose + hi/lo split (used once, for x) -----
__global__ __launch_bounds__(256)
void transpose_split(const float* __restrict__ X, unsigned short* __restrict__ Hi,
                     unsigned short* __restrict__ Lo) {
  __shared__ float tile[64][68];
  const int b = blockIdx.z;
  const int c0 = blockIdx.y * 64;
  const int t0 = blockIdx.x * 64;
  const int tid = threadIdx.x;
  {
    const int cl = tid >> 2, tg = tid & 3;
    const float* src = X + ((size_t)b * C_ + c0 + cl) * T_ + t0 + tg * 16;
    float4 v0 = *(const float4*)(src);
    float4 v1 = *(const float4*)(src + 4);
    float4 v2 = *(const float4*)(src + 8);
    float4 v3 = *(const float4*)(src + 12);
    float* d = &tile[cl][tg * 16];
    *(float4*)(d) = v0; *(float4*)(d + 4) = v1;
    *(float4*)(d + 8) = v2; *(float4*)(d + 12) = v3;
  }
  __syncthreads();
  {
    const int tl = tid >> 2, cg = tid & 3;
    u16x8 h0, h1, l0, l1;
#pragma unroll
    for (int j = 0; j < 16; ++j) {
      const float v = tile[cg * 16 + j][tl];
      const unsigned short hb = bf16_rne(v);
      const float hf = __builtin_bit_cast(float, (unsigned int)hb << 16);
      const unsigned short lb = bf16_rne(v - hf);
      if (j < 8) { h0[j] = hb; l0[j] = lb; }
      else       { h1[j - 8] = hb; l1[j - 8] = lb; }
    }
    const size_t off = ((size_t)b * T_ + t0 + tl) * C_ + c0 + cg * 16;
    *(u16x8*)(Hi + off) = h0; *(u16x8*)(Hi + off + 8) = h1;
    *(u16x8*)(Lo + off) = l0; *(u16x8*)(Lo + off + 8) = l1;
  }
}

// ------------------------------- MFMA conv ----------------------------------
// Block: 128 co x 128 t, 256 threads (4 waves), wave = 128 co x 32 t
// (8 m-tiles x 2 n-tiles of 16x16). K-chunks of 32 ci; taps via t-shifts.
// Double-buffered LDS staging, ONE barrier per cc iteration.
template <int DIL, bool SNAKE, bool PLANES, bool WF32>
__global__ __launch_bounds__(256, 3)
void conv_mfma(const unsigned short* __restrict__ Xhi,  // [b][T][C] bf16 bits
               const unsigned short* __restrict__ Xlo,
               const unsigned short* __restrict__ Wq,   // frag-swizzled
               const float* __restrict__ svec,
               const float* __restrict__ bias, const float* __restrict__ aexp,
               const float* __restrict__ invb,
               const float* __restrict__ res,           // fp32 [b][co][t]
               float* __restrict__ Y,                   // fp32 [b][co][t]
               unsigned short* __restrict__ Ohi,        // [b][T][C] planes
               unsigned short* __restrict__ Olo) {
  constexpr int TT = 128;
  constexpr int R = TT + 2 * DIL;
  constexpr int RW = 40;           // padded row stride (80 B): 2-way banks, free
  constexpr int XU = R * 8;        // 16 B staging units per buffer
  constexpr int NIT = (XU + 255) / 256;
  __shared__ unsigned short Xs[2][2][R * RW];  // [buf][plane][...]

  const int b = blockIdx.z;
  const int co0 = blockIdx.y * 128;
  const int cob = blockIdx.y * 8;
  const int t0 = blockIdx.x * TT;
  const int tid = threadIdx.x;
  const int lane = tid & 63;
  const int wv = tid >> 6;
  const int l15 = lane & 15;
  const int quad = lane >> 4;

  f32x4 acc[8][2] = {};

  const size_t xbase = (size_t)b * T_ * C_;

  auto stage_gload = [&](int cc, u16x8* st) {
#pragma unroll
    for (int it = 0; it < NIT; ++it) {
      const int u = it * 256 + tid;
      u16x8 v = {0, 0, 0, 0, 0, 0, 0, 0};
      if (u < XU) {
        const int r = u >> 3, sub = u & 7;
        const int pl = sub >> 2, g = sub & 3;
        const int t = t0 - DIL + r;
        if ((unsigned)t < (unsigned)T_)
          v = *(const u16x8*)((pl ? Xlo : Xhi) + xbase + (size_t)t * C_ + cc * 32 + g * 8);
      }
      st[it] = v;
    }
  };
  auto stage_swrite = [&](int buf, const u16x8* st) {
#pragma unroll
    for (int it = 0; it < NIT; ++it) {
      const int u = it * 256 + tid;
      if (u < XU) {
        const int r = u >> 3, sub = u & 7;
        const int pl = sub >> 2, g = sub & 3;
        *(u16x8*)&Xs[buf][pl][r * RW + g * 8] = st[it];
      }
    }
  };

  u16x8 st[NIT];
  stage_gload(0, st);
  stage_swrite(0, st);
  __syncthreads();

#pragma unroll 1
  for (int cc = 0; cc < C_ / 32; ++cc) {
    const int cur = cc & 1;
    if (cc < C_ / 32 - 1) stage_gload(cc + 1, st);  // prefetch, no wait yet

#pragma unroll
    for (int tap = 0; tap < K_; ++tap) {
      const unsigned short* wb =
          Wq + ((((size_t)cc * K_ + tap) * 32 + cob) * 512) + (size_t)lane * 8;
      bf16x8 a[8];
#pragma unroll
      for (int m = 0; m < 8; ++m)
        a[m] = __builtin_bit_cast(bf16x8, *(const u16x8*)(wb + m * 512));
#pragma unroll
      for (int n = 0; n < 2; ++n) {
        const int r = wv * 32 + n * 16 + l15 + tap * DIL;
        const bf16x8 bh =
            __builtin_bit_cast(bf16x8, *(const u16x8*)&Xs[cur][0][r * RW + quad * 8]);
        const bf16x8 bl =
            __builtin_bit_cast(bf16x8, *(const u16x8*)&Xs[cur][1][r * RW + quad * 8]);
#pragma unroll
        for (int m = 0; m < 8; ++m) {
          acc[m][n] = __builtin_amdgcn_mfma_f32_16x16x32_bf16(a[m], bh, acc[m][n], 0, 0, 0);
          acc[m][n] = __builtin_amdgcn_mfma_f32_16x16x32_bf16(a[m], bl, acc[m][n], 0, 0, 0);
        }
      }
    }

    if (cc < C_ / 32 - 1) stage_swrite(1 - cur, st);  // waits its own vmcnt
    __syncthreads();  // single barrier per iteration
  }

  // ---- fused epilogue ----
  const float sw = *svec;

  if (PLANES) {
    // Transpose through LDS so plane stores are 32B-contiguous.
    uint32_t* E = (uint32_t*)&Xs[0][0][0];  // 128 x 33 u32 = 16.9 KB (fits buf0)
    constexpr int ELD = 33;
#pragma unroll 1
    for (int mb = 0; mb < 4; ++mb) {  // chunks of 2 m-tiles = 32 co
      __syncthreads();                // protect E from previous chunk's readers
#pragma unroll
      for (int mm = 0; mm < 2; ++mm) {
        const int m = mb * 2 + mm;
        const int cb = co0 + m * 16 + quad * 4;
        float bs[4], av[4], ibv[4];
#pragma unroll
        for (int reg = 0; reg < 4; ++reg) {
          bs[reg] = bias[cb + reg];
          if (SNAKE) { av[reg] = aexp[cb + reg]; ibv[reg] = invb[cb + reg]; }
        }
#pragma unroll
        for (int n = 0; n < 2; ++n) {
          const int tl = wv * 32 + n * 16 + l15;
          const int t = t0 + tl;
#pragma unroll
          for (int reg = 0; reg < 4; ++reg) {
            float v = sw * acc[m][n][reg] + bs[reg];
            if (SNAKE) {
              const float sn = __sinf(av[reg] * v);
              v = v + ibv[reg] * sn * sn;
            } else {
              v = v + res[((size_t)b * C_ + cb + reg) * T_ + t];
            }
            if (WF32) Y[((size_t)b * C_ + cb + reg) * T_ + t] = v;
            const unsigned short hb = bf16_rne(v);
            const float hf = __builtin_bit_cast(float, (unsigned int)hb << 16);
            const unsigned short lb = bf16_rne(v - hf);
            E[tl * ELD + mm * 16 + quad * 4 + reg] =
                ((unsigned int)hb << 16) | (unsigned int)lb;
          }
        }
      }
      __syncthreads();
      // coalesced store phase: each thread handles 16 consecutive co of one t
      {
        const int row = tid >> 1, half = tid & 1;
        uint32_t u[16];
#pragma unroll
        for (int j = 0; j < 16; ++j) u[j] = E[row * ELD + half * 16 + j];
        u16x8 hA, hB, lA, lB;
#pragma unroll
        for (int j = 0; j < 8; ++j) {
          hA[j] = (unsigned short)(u[j] >> 16);
          lA[j] = (unsigned short)(u[j] & 0xFFFFu);
          hB[j] = (unsigned short)(u[8 + j] >> 16);
          lB[j] = (unsigned short)(u[8 + j] & 0xFFFFu);
        }
        const size_t poff = ((size_t)b * T_ + t0 + row) * C_ + co0 + mb * 32 + half * 16;
        *(u16x8*)(Ohi + poff) = hA; *(u16x8*)(Ohi + poff + 8) = hB;
        *(u16x8*)(Olo + poff) = lA; *(u16x8*)(Olo + poff + 8) = lB;
      }
    }
  } else {
    // fp32-only epilogue (already coalesced along t)
#pragma unroll
    for (int m = 0; m < 8; ++m) {
      const int cb = co0 + m * 16 + quad * 4;
      float bs[4], av[4], ibv[4];
#pragma unroll
      for (int reg = 0; reg < 4; ++reg) {
        bs[reg] = bias[cb + reg];
        if (SNAKE) { av[reg] = aexp[cb + reg]; ibv[reg] = invb[cb + reg]; }
      }
#pragma unroll
      for (int n = 0; n < 2; ++n) {
        const int t = t0 + wv * 32 + n * 16 + l15;
#pragma unroll
        for (int reg = 0; reg < 4; ++reg) {
          float v = sw * acc[m][n][reg] + bs[reg];
          if (SNAKE) {
            const float sn = __sinf(av[reg] * v);
            v = v + ibv[reg] * sn * sn;
          } else {
            v = v + res[((size_t)b * C_ + cb + reg) * T_ + t];
          }
          Y[((size_t)b * C_ + cb + reg) * T_ + t] = v;
        }
      }
    }
  }
}

// ------------------------------- launch -------------------------------------
extern "C" void kernel_launch(void* const* d_in, const int* in_sizes, int n_in,
                              void* d_out, int out_size, void* d_ws, size_t ws_size,
                              hipStream_t stream) {
  (void)in_sizes; (void)n_in; (void)out_size; (void)ws_size;
  const float* x = (const float*)d_in[0];
  const float* w1 = (const float*)d_in[1];
  const float* b1 = (const float*)d_in[2];
  const float* al = (const float*)d_in[3];
  const float* be = (const float*)d_in[4];
  const float* w2 = (const float*)d_in[5];
  const float* b2 = (const float*)d_in[6];
  float* out = (float*)d_out;
  char* wsb = (char*)d_ws;

  float* part = (float*)(wsb + OFF_PART);
  float* svec = (float*)(wsb + OFF_S);
  float* ae = (float*)(wsb + OFF_AE);
  float* ib = (float*)(wsb + OFF_IB);
  unsigned short* wq1 = (unsigned short*)(wsb + OFF_WQ1);
  unsigned short* wq2 = (unsigned short*)(wsb + OFF_WQ2);
  unsigned short* Phi = (unsigned short*)(wsb + OFF_PHI);
  unsigned short* Plo = (unsigned short*)(wsb + OFF_PLO);
  unsigned short* Qhi = (unsigned short*)(wsb + OFF_QHI);
  unsigned short* Qlo = (unsigned short*)(wsb + OFF_QLO);

  absmean_partial<<<dim3(96, 6), 256, 0, stream>>>(w1, w2, part);
  absmean_final<<<6, 128, 0, stream>>>(part, svec);
  quantize_kernel<<<(3 * WELEM) / 256, 256, 0, stream>>>(w1, wq1, svec, 0);
  quantize_kernel<<<(3 * WELEM) / 256, 256, 0, stream>>>(w2, wq2, svec, 3);
  snake_params_kernel<<<6, 256, 0, stream>>>(al, be, ae, ib);

  const dim3 tgrid(T_ / 64, C_ / 64, B_);
  const dim3 cgrid(T_ / 128, C_ / 128, B_);

  transpose_split<<<tgrid, 256, 0, stream>>>(x, Phi, Plo);

  // stage 0 (dil=1): conv1 P->Q planes; conv2 Q->out fp32 + P planes
  conv_mfma<1, true, true, false><<<cgrid, 256, 0, stream>>>(
      Phi, Plo, wq1 + 0 * (size_t)WELEM, svec + 0, b1 + 0, ae + 0, ib + 0,
      nullptr, nullptr, Qhi, Qlo);
  conv_mfma<1, false, true, true><<<cgrid, 256, 0, stream>>>(
      Qhi, Qlo, wq2 + 0 * (size_t)WELEM, svec + 3, b2 + 0, nullptr, nullptr,
      x, out, Phi, Plo);

  // stage 1 (dil=3)
  conv_mfma<3, true, true, false><<<cgrid, 256, 0, stream>>>(
      Phi, Plo, wq1 + 1 * (size_t)WELEM, svec + 1, b1 + C_, ae + C_, ib + C_,
      nullptr, nullptr, Qhi, Qlo);
  conv_mfma<1, false, true, true><<<cgrid, 256, 0, stream>>>(
      Qhi, Qlo, wq2 + 1 * (size_t)WELEM, svec + 4, b2 + C_, nullptr, nullptr,
      out, out, Phi, Plo);

  // stage 2 (dil=5): final conv2 writes fp32 only
  conv_mfma<5, true, true, false><<<cgrid, 256, 0, stream>>>(
      Phi, Plo, wq1 + 2 * (size_t)WELEM, svec + 2, b1 + 2 * C_, ae + 2 * C_,
      ib + 2 * C_, nullptr, nullptr, Qhi, Qlo);
  conv_mfma<1, false, false, true><<<cgrid, 256, 0, stream>>>(
      Qhi, Qlo, wq2 + 2 * (size_t)WELEM, svec + 5, b2 + 2 * C_, nullptr, nullptr,
      out, out, nullptr, nullptr);
}

// Round 6
// 2586.014 us; speedup vs baseline: 1.1930x; 1.1930x over previous
//
#include <hip/hip_runtime.h>
#include <math.h>
#include <stdint.h>

// ---------------------------------------------------------------------------
// BitResidualBlock via bf16-split MFMA.
// R6: R2's known-good 2-barrier K-loop (TT=256, 8m x 4n, LB(256,2)) +
// R5's LDS-transposed coalesced plane epilogue (64B-contiguous stores).
// R5's register-prefetch dbuf is REVERTED (it spilled: 2.8 GB scratch/dispatch).
// ---------------------------------------------------------------------------

constexpr int B_ = 8, C_ = 512, T_ = 4096, K_ = 3;
constexpr int WELEM = C_ * C_ * K_;  // 786432 per tensor

typedef __bf16 bf16x8 __attribute__((ext_vector_type(8)));
typedef float f32x4 __attribute__((ext_vector_type(4)));
typedef unsigned short u16x8 __attribute__((ext_vector_type(8)));

// ws byte offsets
constexpr size_t OFF_PART = 0;
constexpr size_t OFF_S = 4096;
constexpr size_t OFF_AE = 8192;
constexpr size_t OFF_IB = 16384;
constexpr size_t OFF_WQ1 = 32768;  // ushort[3*WELEM], frag-swizzled
constexpr size_t OFF_WQ2 = OFF_WQ1 + (size_t)3 * WELEM * 2;
constexpr size_t NBCT = (size_t)B_ * C_ * T_;
constexpr size_t OFF_PHI = OFF_WQ2 + (size_t)3 * WELEM * 2;  // bf16 planes
constexpr size_t OFF_PLO = OFF_PHI + NBCT * 2;
constexpr size_t OFF_QHI = OFF_PLO + NBCT * 2;
constexpr size_t OFF_QLO = OFF_QHI + NBCT * 2;

__device__ inline unsigned short bf16_rne(float v) {
  unsigned int u = __builtin_bit_cast(unsigned int, v);
  unsigned int r = u + 0x7FFFu + ((u >> 16) & 1u);
  return (unsigned short)(r >> 16);
}

// --------------------------- absmean (deterministic) ------------------------
__global__ __launch_bounds__(256)
void absmean_partial(const float* __restrict__ w1, const float* __restrict__ w2,
                     float* __restrict__ part) {
  __shared__ float red[256];
  const int t = blockIdx.y;
  const float* src = (t < 3) ? (w1 + (size_t)t * WELEM) : (w2 + (size_t)(t - 3) * WELEM);
  const int base = blockIdx.x * (256 * 32);
  float v = 0.f;
#pragma unroll
  for (int j = 0; j < 32; ++j) v += fabsf(src[base + j * 256 + threadIdx.x]);
  red[threadIdx.x] = v;
  __syncthreads();
  for (int s = 128; s > 0; s >>= 1) {
    if (threadIdx.x < (unsigned)s) red[threadIdx.x] += red[threadIdx.x + s];
    __syncthreads();
  }
  if (threadIdx.x == 0) part[t * 96 + blockIdx.x] = red[0];
}

__global__ __launch_bounds__(128)
void absmean_final(const float* __restrict__ part, float* __restrict__ svec) {
  __shared__ float red[128];
  const int t = blockIdx.x;
  red[threadIdx.x] = (threadIdx.x < 96) ? part[t * 96 + threadIdx.x] : 0.f;
  __syncthreads();
  for (int s = 64; s > 0; s >>= 1) {
    if (threadIdx.x < (unsigned)s) red[threadIdx.x] += red[threadIdx.x + s];
    __syncthreads();
  }
  if (threadIdx.x == 0) svec[t] = red[0] / (float)WELEM;
}

// --------------------------- quantize -> ternary bf16, frag-swizzled --------
// dst layout: idx = (((st*16 + cc)*3 + tap)*32 + cot)*512 + lane*8 + j
//   where co = cot*16 + (lane&15), ci = cc*32 + (lane>>4)*8 + j.
__global__ __launch_bounds__(256)
void quantize_kernel(const float* __restrict__ src, unsigned short* __restrict__ dst,
                     const float* __restrict__ svec, int sbase) {
  const int idx = blockIdx.x * 256 + threadIdx.x;  // exact grid over 3*WELEM
  const int j = idx & 7;
  const int lane = (idx >> 3) & 63;
  const int cot = (idx >> 9) & 31;
  const int rest = idx >> 14;
  const int tap = rest % 3;
  const int rest2 = rest / 3;
  const int cc = rest2 & 15;
  const int st = rest2 >> 4;
  const int co = cot * 16 + (lane & 15);
  const int ci = cc * 32 + (lane >> 4) * 8 + j;
  const float s = svec[sbase + st];
  const float w = src[(((size_t)st * C_ + co) * C_ + ci) * K_ + tap];
  float q = rintf(w / (s + 1e-5f));
  q = fminf(1.f, fmaxf(-1.f, q));
  dst[idx] = (unsigned short)(__builtin_bit_cast(unsigned int, q) >> 16);
}

__global__ __launch_bounds__(256)
void snake_params_kernel(const float* __restrict__ al, const float* __restrict__ be,
                         float* __restrict__ ae, float* __restrict__ ib) {
  const int idx = blockIdx.x * 256 + threadIdx.x;
  if (idx < 3 * C_) {
    ae[idx] = expf(al[idx]);
    ib[idx] = 1.f / (expf(be[idx]) + 1e-9f);
  }
}

// --------------------------- transpose + hi/lo split (used once, for x) -----
__global__ __launch_bounds__(256)
void transpose_split(const float* __restrict__ X, unsigned short* __restrict__ Hi,
                     unsigned short* __restrict__ Lo) {
  __shared__ float tile[64][68];
  const int b = blockIdx.z;
  const int c0 = blockIdx.y * 64;
  const int t0 = blockIdx.x * 64;
  const int tid = threadIdx.x;
  {
    const int cl = tid >> 2, tg = tid & 3;
    const float* src = X + ((size_t)b * C_ + c0 + cl) * T_ + t0 + tg * 16;
    float4 v0 = *(const float4*)(src);
    float4 v1 = *(const float4*)(src + 4);
    float4 v2 = *(const float4*)(src + 8);
    float4 v3 = *(const float4*)(src + 12);
    float* d = &tile[cl][tg * 16];
    *(float4*)(d) = v0; *(float4*)(d + 4) = v1;
    *(float4*)(d + 8) = v2; *(float4*)(d + 12) = v3;
  }
  __syncthreads();
  {
    const int tl = tid >> 2, cg = tid & 3;
    u16x8 h0, h1, l0, l1;
#pragma unroll
    for (int j = 0; j < 16; ++j) {
      const float v = tile[cg * 16 + j][tl];
      const unsigned short hb = bf16_rne(v);
      const float hf = __builtin_bit_cast(float, (unsigned int)hb << 16);
      const unsigned short lb = bf16_rne(v - hf);
      if (j < 8) { h0[j] = hb; l0[j] = lb; }
      else       { h1[j - 8] = hb; l1[j - 8] = lb; }
    }
    const size_t off = ((size_t)b * T_ + t0 + tl) * C_ + c0 + cg * 16;
    *(u16x8*)(Hi + off) = h0; *(u16x8*)(Hi + off + 8) = h1;
    *(u16x8*)(Lo + off) = l0; *(u16x8*)(Lo + off + 8) = l1;
  }
}

// ------------------------------- MFMA conv ----------------------------------
// Block: 128 co x 256 t, 256 threads (4 waves), wave = 128 co x 64 t
// (8 m-tiles x 4 n-tiles of 16x16). K-chunks of 32 ci; taps via t-shifts.
// R2's 2-barrier loop (no register prefetch).
template <int DIL, bool SNAKE, bool PLANES, bool WF32>
__global__ __launch_bounds__(256, 2)
void conv_mfma(const unsigned short* __restrict__ Xhi,  // [b][T][C] bf16 bits
               const unsigned short* __restrict__ Xlo,
               const unsigned short* __restrict__ Wq,   // frag-swizzled
               const float* __restrict__ svec,
               const float* __restrict__ bias, const float* __restrict__ aexp,
               const float* __restrict__ invb,
               const float* __restrict__ res,           // fp32 [b][co][t]
               float* __restrict__ Y,                   // fp32 [b][co][t]
               unsigned short* __restrict__ Ohi,        // [b][T][C] planes
               unsigned short* __restrict__ Olo) {
  constexpr int TT = 256;
  constexpr int R = TT + 2 * DIL;
  constexpr int RW = 40;  // padded row stride (80 B): 2-way banks, free
  __shared__ unsigned short Xs[2][R * RW];

  const int b = blockIdx.z;
  const int co0 = blockIdx.y * 128;
  const int cob = blockIdx.y * 8;
  const int t0 = blockIdx.x * TT;
  const int tid = threadIdx.x;
  const int lane = tid & 63;
  const int wv = tid >> 6;
  const int l15 = lane & 15;
  const int quad = lane >> 4;

  f32x4 acc[8][4] = {};

  const size_t xbase = (size_t)b * T_ * C_;

#pragma unroll 1
  for (int cc = 0; cc < C_ / 32; ++cc) {
    constexpr int XU = R * 8;  // 16 B units
#pragma unroll
    for (int it = 0; it < (XU + 255) / 256; ++it) {
      const int u = it * 256 + tid;
      if (u < XU) {
        const int r = u >> 3, sub = u & 7;
        const int pl = sub >> 2, g = sub & 3;
        const int t = t0 - DIL + r;
        u16x8 v = {0, 0, 0, 0, 0, 0, 0, 0};
        if ((unsigned)t < (unsigned)T_)
          v = *(const u16x8*)((pl ? Xlo : Xhi) + xbase + (size_t)t * C_ + cc * 32 + g * 8);
        *(u16x8*)&Xs[pl][r * RW + g * 8] = v;
      }
    }
    __syncthreads();

#pragma unroll 1
    for (int tap = 0; tap < K_; ++tap) {
      const unsigned short* wb =
          Wq + ((((size_t)cc * K_ + tap) * 32 + cob) * 512) + (size_t)lane * 8;
      bf16x8 a[8];
#pragma unroll
      for (int m = 0; m < 8; ++m)
        a[m] = __builtin_bit_cast(bf16x8, *(const u16x8*)(wb + m * 512));
#pragma unroll
      for (int n = 0; n < 4; ++n) {
        const int r = wv * 64 + n * 16 + l15 + tap * DIL;
        const bf16x8 bh = __builtin_bit_cast(bf16x8, *(const u16x8*)&Xs[0][r * RW + quad * 8]);
        const bf16x8 bl = __builtin_bit_cast(bf16x8, *(const u16x8*)&Xs[1][r * RW + quad * 8]);
#pragma unroll
        for (int m = 0; m < 8; ++m) {
          acc[m][n] = __builtin_amdgcn_mfma_f32_16x16x32_bf16(a[m], bh, acc[m][n], 0, 0, 0);
          acc[m][n] = __builtin_amdgcn_mfma_f32_16x16x32_bf16(a[m], bl, acc[m][n], 0, 0, 0);
        }
      }
    }
    __syncthreads();
  }

  // ---- fused epilogue ----
  const float sw = *svec;

  if (PLANES) {
    // Round-trip through LDS so plane stores are 64B-contiguous per thread.
    uint32_t* E = (uint32_t*)&Xs[0][0];  // 256 x 33 u32 = 33.8 KB (Xs >= 41 KB)
    constexpr int ELD = 33;
#pragma unroll 1
    for (int mb = 0; mb < 4; ++mb) {  // chunks of 2 m-tiles = 32 co
      __syncthreads();                // protect E from previous phase readers
#pragma unroll
      for (int mm = 0; mm < 2; ++mm) {
        const int m = mb * 2 + mm;
        const int cb = co0 + m * 16 + quad * 4;
        float bs[4], av[4], ibv[4];
#pragma unroll
        for (int reg = 0; reg < 4; ++reg) {
          bs[reg] = bias[cb + reg];
          if (SNAKE) { av[reg] = aexp[cb + reg]; ibv[reg] = invb[cb + reg]; }
        }
#pragma unroll
        for (int n = 0; n < 4; ++n) {
          const int tl = wv * 64 + n * 16 + l15;
          const int t = t0 + tl;
#pragma unroll
          for (int reg = 0; reg < 4; ++reg) {
            float v = sw * acc[m][n][reg] + bs[reg];
            if (SNAKE) {
              const float sn = __sinf(av[reg] * v);
              v = v + ibv[reg] * sn * sn;
            } else {
              v = v + res[((size_t)b * C_ + cb + reg) * T_ + t];
            }
            if (WF32) Y[((size_t)b * C_ + cb + reg) * T_ + t] = v;
            const unsigned short hb = bf16_rne(v);
            const float hf = __builtin_bit_cast(float, (unsigned int)hb << 16);
            const unsigned short lb = bf16_rne(v - hf);
            E[tl * ELD + mm * 16 + quad * 4 + reg] =
                ((unsigned int)hb << 16) | (unsigned int)lb;
          }
        }
      }
      __syncthreads();
      // coalesced store phase: thread = t-row, 32 consecutive co (64 B/plane)
      {
        const int row = tid;
        uint32_t u[32];
#pragma unroll
        for (int j = 0; j < 32; ++j) u[j] = E[row * ELD + j];
        u16x8 hq[4], lq[4];
#pragma unroll
        for (int g = 0; g < 4; ++g)
#pragma unroll
          for (int j = 0; j < 8; ++j) {
            hq[g][j] = (unsigned short)(u[g * 8 + j] >> 16);
            lq[g][j] = (unsigned short)(u[g * 8 + j] & 0xFFFFu);
          }
        const size_t poff = ((size_t)b * T_ + t0 + row) * C_ + co0 + mb * 32;
#pragma unroll
        for (int g = 0; g < 4; ++g) {
          *(u16x8*)(Ohi + poff + g * 8) = hq[g];
          *(u16x8*)(Olo + poff + g * 8) = lq[g];
        }
      }
    }
  } else {
    // fp32-only epilogue (coalesced along t)
#pragma unroll
    for (int m = 0; m < 8; ++m) {
      const int cb = co0 + m * 16 + quad * 4;
      float bs[4], av[4], ibv[4];
#pragma unroll
      for (int reg = 0; reg < 4; ++reg) {
        bs[reg] = bias[cb + reg];
        if (SNAKE) { av[reg] = aexp[cb + reg]; ibv[reg] = invb[cb + reg]; }
      }
#pragma unroll
      for (int n = 0; n < 4; ++n) {
        const int t = t0 + wv * 64 + n * 16 + l15;
#pragma unroll
        for (int reg = 0; reg < 4; ++reg) {
          float v = sw * acc[m][n][reg] + bs[reg];
          if (SNAKE) {
            const float sn = __sinf(av[reg] * v);
            v = v + ibv[reg] * sn * sn;
          } else {
            v = v + res[((size_t)b * C_ + cb + reg) * T_ + t];
          }
          Y[((size_t)b * C_ + cb + reg) * T_ + t] = v;
        }
      }
    }
  }
}

// ------------------------------- launch -------------------------------------
extern "C" void kernel_launch(void* const* d_in, const int* in_sizes, int n_in,
                              void* d_out, int out_size, void* d_ws, size_t ws_size,
                              hipStream_t stream) {
  (void)in_sizes; (void)n_in; (void)out_size; (void)ws_size;
  const float* x = (const float*)d_in[0];
  const float* w1 = (const float*)d_in[1];
  const float* b1 = (const float*)d_in[2];
  const float* al = (const float*)d_in[3];
  const float* be = (const float*)d_in[4];
  const float* w2 = (const float*)d_in[5];
  const float* b2 = (const float*)d_in[6];
  float* out = (float*)d_out;
  char* wsb = (char*)d_ws;

  float* part = (float*)(wsb + OFF_PART);
  float* svec = (float*)(wsb + OFF_S);
  float* ae = (float*)(wsb + OFF_AE);
  float* ib = (float*)(wsb + OFF_IB);
  unsigned short* wq1 = (unsigned short*)(wsb + OFF_WQ1);
  unsigned short* wq2 = (unsigned short*)(wsb + OFF_WQ2);
  unsigned short* Phi = (unsigned short*)(wsb + OFF_PHI);
  unsigned short* Plo = (unsigned short*)(wsb + OFF_PLO);
  unsigned short* Qhi = (unsigned short*)(wsb + OFF_QHI);
  unsigned short* Qlo = (unsigned short*)(wsb + OFF_QLO);

  absmean_partial<<<dim3(96, 6), 256, 0, stream>>>(w1, w2, part);
  absmean_final<<<6, 128, 0, stream>>>(part, svec);
  quantize_kernel<<<(3 * WELEM) / 256, 256, 0, stream>>>(w1, wq1, svec, 0);
  quantize_kernel<<<(3 * WELEM) / 256, 256, 0, stream>>>(w2, wq2, svec, 3);
  snake_params_kernel<<<6, 256, 0, stream>>>(al, be, ae, ib);

  const dim3 tgrid(T_ / 64, C_ / 64, B_);
  const dim3 cgrid(T_ / 256, C_ / 128, B_);

  transpose_split<<<tgrid, 256, 0, stream>>>(x, Phi, Plo);

  // stage 0 (dil=1): conv1 P->Q planes; conv2 Q->out fp32 + P planes
  conv_mfma<1, true, true, false><<<cgrid, 256, 0, stream>>>(
      Phi, Plo, wq1 + 0 * (size_t)WELEM, svec + 0, b1 + 0, ae + 0, ib + 0,
      nullptr, nullptr, Qhi, Qlo);
  conv_mfma<1, false, true, true><<<cgrid, 256, 0, stream>>>(
      Qhi, Qlo, wq2 + 0 * (size_t)WELEM, svec + 3, b2 + 0, nullptr, nullptr,
      x, out, Phi, Plo);

  // stage 1 (dil=3)
  conv_mfma<3, true, true, false><<<cgrid, 256, 0, stream>>>(
      Phi, Plo, wq1 + 1 * (size_t)WELEM, svec + 1, b1 + C_, ae + C_, ib + C_,
      nullptr, nullptr, Qhi, Qlo);
  conv_mfma<1, false, true, true><<<cgrid, 256, 0, stream>>>(
      Qhi, Qlo, wq2 + 1 * (size_t)WELEM, svec + 4, b2 + C_, nullptr, nullptr,
      out, out, Phi, Plo);

  // stage 2 (dil=5): final conv2 writes fp32 only
  conv_mfma<5, true, true, false><<<cgrid, 256, 0, stream>>>(
      Phi, Plo, wq1 + 2 * (size_t)WELEM, svec + 2, b1 + 2 * C_, ae + 2 * C_,
      ib + 2 * C_, nullptr, nullptr, Qhi, Qlo);
  conv_mfma<1, false, false, true><<<cgrid, 256, 0, stream>>>(
      Qhi, Qlo, wq2 + 2 * (size_t)WELEM, svec + 5, b2 + 2 * C_, nullptr, nullptr,
      out, out, nullptr, nullptr);
}

// Round 7
// 842.290 us; speedup vs baseline: 3.6628x; 3.0702x over previous
//
#include <hip/hip_runtime.h>
#include <math.h>
#include <stdint.h>

// ---------------------------------------------------------------------------
// BitResidualBlock via bf16-split MFMA.
// R7: R6 with the epilogue chunk loop FULLY UNROLLED. R5/R6 regressed because
// `#pragma unroll 1` made `acc[mb*2+mm]` a runtime register-array index ->
// compiler demoted the whole accumulator to scratch (1.8 GB traffic, MfmaUtil
// 8%). All acc indices must be compile-time constants.
// ---------------------------------------------------------------------------

constexpr int B_ = 8, C_ = 512, T_ = 4096, K_ = 3;
constexpr int WELEM = C_ * C_ * K_;  // 786432 per tensor

typedef __bf16 bf16x8 __attribute__((ext_vector_type(8)));
typedef float f32x4 __attribute__((ext_vector_type(4)));
typedef unsigned short u16x8 __attribute__((ext_vector_type(8)));

// ws byte offsets
constexpr size_t OFF_PART = 0;
constexpr size_t OFF_S = 4096;
constexpr size_t OFF_AE = 8192;
constexpr size_t OFF_IB = 16384;
constexpr size_t OFF_WQ1 = 32768;  // ushort[3*WELEM], frag-swizzled
constexpr size_t OFF_WQ2 = OFF_WQ1 + (size_t)3 * WELEM * 2;
constexpr size_t NBCT = (size_t)B_ * C_ * T_;
constexpr size_t OFF_PHI = OFF_WQ2 + (size_t)3 * WELEM * 2;  // bf16 planes
constexpr size_t OFF_PLO = OFF_PHI + NBCT * 2;
constexpr size_t OFF_QHI = OFF_PLO + NBCT * 2;
constexpr size_t OFF_QLO = OFF_QHI + NBCT * 2;

__device__ inline unsigned short bf16_rne(float v) {
  unsigned int u = __builtin_bit_cast(unsigned int, v);
  unsigned int r = u + 0x7FFFu + ((u >> 16) & 1u);
  return (unsigned short)(r >> 16);
}

// --------------------------- absmean (deterministic) ------------------------
__global__ __launch_bounds__(256)
void absmean_partial(const float* __restrict__ w1, const float* __restrict__ w2,
                     float* __restrict__ part) {
  __shared__ float red[256];
  const int t = blockIdx.y;
  const float* src = (t < 3) ? (w1 + (size_t)t * WELEM) : (w2 + (size_t)(t - 3) * WELEM);
  const int base = blockIdx.x * (256 * 32);
  float v = 0.f;
#pragma unroll
  for (int j = 0; j < 32; ++j) v += fabsf(src[base + j * 256 + threadIdx.x]);
  red[threadIdx.x] = v;
  __syncthreads();
  for (int s = 128; s > 0; s >>= 1) {
    if (threadIdx.x < (unsigned)s) red[threadIdx.x] += red[threadIdx.x + s];
    __syncthreads();
  }
  if (threadIdx.x == 0) part[t * 96 + blockIdx.x] = red[0];
}

__global__ __launch_bounds__(128)
void absmean_final(const float* __restrict__ part, float* __restrict__ svec) {
  __shared__ float red[128];
  const int t = blockIdx.x;
  red[threadIdx.x] = (threadIdx.x < 96) ? part[t * 96 + threadIdx.x] : 0.f;
  __syncthreads();
  for (int s = 64; s > 0; s >>= 1) {
    if (threadIdx.x < (unsigned)s) red[threadIdx.x] += red[threadIdx.x + s];
    __syncthreads();
  }
  if (threadIdx.x == 0) svec[t] = red[0] / (float)WELEM;
}

// --------------------------- quantize -> ternary bf16, frag-swizzled --------
// dst layout: idx = (((st*16 + cc)*3 + tap)*32 + cot)*512 + lane*8 + j
//   where co = cot*16 + (lane&15), ci = cc*32 + (lane>>4)*8 + j.
__global__ __launch_bounds__(256)
void quantize_kernel(const float* __restrict__ src, unsigned short* __restrict__ dst,
                     const float* __restrict__ svec, int sbase) {
  const int idx = blockIdx.x * 256 + threadIdx.x;  // exact grid over 3*WELEM
  const int j = idx & 7;
  const int lane = (idx >> 3) & 63;
  const int cot = (idx >> 9) & 31;
  const int rest = idx >> 14;
  const int tap = rest % 3;
  const int rest2 = rest / 3;
  const int cc = rest2 & 15;
  const int st = rest2 >> 4;
  const int co = cot * 16 + (lane & 15);
  const int ci = cc * 32 + (lane >> 4) * 8 + j;
  const float s = svec[sbase + st];
  const float w = src[(((size_t)st * C_ + co) * C_ + ci) * K_ + tap];
  float q = rintf(w / (s + 1e-5f));
  q = fminf(1.f, fmaxf(-1.f, q));
  dst[idx] = (unsigned short)(__builtin_bit_cast(unsigned int, q) >> 16);
}

__global__ __launch_bounds__(256)
void snake_params_kernel(const float* __restrict__ al, const float* __restrict__ be,
                         float* __restrict__ ae, float* __restrict__ ib) {
  const int idx = blockIdx.x * 256 + threadIdx.x;
  if (idx < 3 * C_) {
    ae[idx] = expf(al[idx]);
    ib[idx] = 1.f / (expf(be[idx]) + 1e-9f);
  }
}

// --------------------------- transpose + hi/lo split (used once, for x) -----
__global__ __launch_bounds__(256)
void transpose_split(const float* __restrict__ X, unsigned short* __restrict__ Hi,
                     unsigned short* __restrict__ Lo) {
  __shared__ float tile[64][68];
  const int b = blockIdx.z;
  const int c0 = blockIdx.y * 64;
  const int t0 = blockIdx.x * 64;
  const int tid = threadIdx.x;
  {
    const int cl = tid >> 2, tg = tid & 3;
    const float* src = X + ((size_t)b * C_ + c0 + cl) * T_ + t0 + tg * 16;
    float4 v0 = *(const float4*)(src);
    float4 v1 = *(const float4*)(src + 4);
    float4 v2 = *(const float4*)(src + 8);
    float4 v3 = *(const float4*)(src + 12);
    float* d = &tile[cl][tg * 16];
    *(float4*)(d) = v0; *(float4*)(d + 4) = v1;
    *(float4*)(d + 8) = v2; *(float4*)(d + 12) = v3;
  }
  __syncthreads();
  {
    const int tl = tid >> 2, cg = tid & 3;
    u16x8 h0, h1, l0, l1;
#pragma unroll
    for (int j = 0; j < 16; ++j) {
      const float v = tile[cg * 16 + j][tl];
      const unsigned short hb = bf16_rne(v);
      const float hf = __builtin_bit_cast(float, (unsigned int)hb << 16);
      const unsigned short lb = bf16_rne(v - hf);
      if (j < 8) { h0[j] = hb; l0[j] = lb; }
      else       { h1[j - 8] = hb; l1[j - 8] = lb; }
    }
    const size_t off = ((size_t)b * T_ + t0 + tl) * C_ + c0 + cg * 16;
    *(u16x8*)(Hi + off) = h0; *(u16x8*)(Hi + off + 8) = h1;
    *(u16x8*)(Lo + off) = l0; *(u16x8*)(Lo + off + 8) = l1;
  }
}

// ------------------------------- MFMA conv ----------------------------------
// Block: 128 co x 256 t, 256 threads (4 waves), wave = 128 co x 64 t
// (8 m-tiles x 4 n-tiles of 16x16). K-chunks of 32 ci; taps via t-shifts.
// R2's 2-barrier loop. Epilogue: LDS-transposed coalesced plane stores,
// ALL register-array indices compile-time (fully unrolled chunk loop).
template <int DIL, bool SNAKE, bool PLANES, bool WF32>
__global__ __launch_bounds__(256, 2)
void conv_mfma(const unsigned short* __restrict__ Xhi,  // [b][T][C] bf16 bits
               const unsigned short* __restrict__ Xlo,
               const unsigned short* __restrict__ Wq,   // frag-swizzled
               const float* __restrict__ svec,
               const float* __restrict__ bias, const float* __restrict__ aexp,
               const float* __restrict__ invb,
               const float* __restrict__ res,           // fp32 [b][co][t]
               float* __restrict__ Y,                   // fp32 [b][co][t]
               unsigned short* __restrict__ Ohi,        // [b][T][C] planes
               unsigned short* __restrict__ Olo) {
  constexpr int TT = 256;
  constexpr int R = TT + 2 * DIL;
  constexpr int RW = 40;  // padded row stride (80 B): 2-way banks, free
  __shared__ unsigned short Xs[2][R * RW];

  const int b = blockIdx.z;
  const int co0 = blockIdx.y * 128;
  const int cob = blockIdx.y * 8;
  const int t0 = blockIdx.x * TT;
  const int tid = threadIdx.x;
  const int lane = tid & 63;
  const int wv = tid >> 6;
  const int l15 = lane & 15;
  const int quad = lane >> 4;

  f32x4 acc[8][4] = {};

  const size_t xbase = (size_t)b * T_ * C_;

#pragma unroll 1
  for (int cc = 0; cc < C_ / 32; ++cc) {
    constexpr int XU = R * 8;  // 16 B units
#pragma unroll
    for (int it = 0; it < (XU + 255) / 256; ++it) {
      const int u = it * 256 + tid;
      if (u < XU) {
        const int r = u >> 3, sub = u & 7;
        const int pl = sub >> 2, g = sub & 3;
        const int t = t0 - DIL + r;
        u16x8 v = {0, 0, 0, 0, 0, 0, 0, 0};
        if ((unsigned)t < (unsigned)T_)
          v = *(const u16x8*)((pl ? Xlo : Xhi) + xbase + (size_t)t * C_ + cc * 32 + g * 8);
        *(u16x8*)&Xs[pl][r * RW + g * 8] = v;
      }
    }
    __syncthreads();

#pragma unroll 1
    for (int tap = 0; tap < K_; ++tap) {
      const unsigned short* wb =
          Wq + ((((size_t)cc * K_ + tap) * 32 + cob) * 512) + (size_t)lane * 8;
      bf16x8 a[8];
#pragma unroll
      for (int m = 0; m < 8; ++m)
        a[m] = __builtin_bit_cast(bf16x8, *(const u16x8*)(wb + m * 512));
#pragma unroll
      for (int n = 0; n < 4; ++n) {
        const int r = wv * 64 + n * 16 + l15 + tap * DIL;
        const bf16x8 bh = __builtin_bit_cast(bf16x8, *(const u16x8*)&Xs[0][r * RW + quad * 8]);
        const bf16x8 bl = __builtin_bit_cast(bf16x8, *(const u16x8*)&Xs[1][r * RW + quad * 8]);
#pragma unroll
        for (int m = 0; m < 8; ++m) {
          acc[m][n] = __builtin_amdgcn_mfma_f32_16x16x32_bf16(a[m], bh, acc[m][n], 0, 0, 0);
          acc[m][n] = __builtin_amdgcn_mfma_f32_16x16x32_bf16(a[m], bl, acc[m][n], 0, 0, 0);
        }
      }
    }
    __syncthreads();
  }

  // ---- fused epilogue ----
  const float sw = *svec;

  if (PLANES) {
    // Round-trip through LDS so plane stores are 64B-contiguous per thread.
    // NOTE: mb loop MUST be fully unrolled (acc indices compile-time).
    uint32_t* E = (uint32_t*)&Xs[0][0];  // 256 x 33 u32 = 33.8 KB (Xs >= 41 KB)
    constexpr int ELD = 33;
#pragma unroll
    for (int mb = 0; mb < 4; ++mb) {  // chunks of 2 m-tiles = 32 co
      __syncthreads();                // protect E from previous phase readers
#pragma unroll
      for (int mm = 0; mm < 2; ++mm) {
        const int m = mb * 2 + mm;
        const int cb = co0 + m * 16 + quad * 4;
        float bs[4], av[4], ibv[4];
#pragma unroll
        for (int reg = 0; reg < 4; ++reg) {
          bs[reg] = bias[cb + reg];
          if (SNAKE) { av[reg] = aexp[cb + reg]; ibv[reg] = invb[cb + reg]; }
        }
#pragma unroll
        for (int n = 0; n < 4; ++n) {
          const int tl = wv * 64 + n * 16 + l15;
          const int t = t0 + tl;
#pragma unroll
          for (int reg = 0; reg < 4; ++reg) {
            float v = sw * acc[m][n][reg] + bs[reg];
            if (SNAKE) {
              const float sn = __sinf(av[reg] * v);
              v = v + ibv[reg] * sn * sn;
            } else {
              v = v + res[((size_t)b * C_ + cb + reg) * T_ + t];
            }
            if (WF32) Y[((size_t)b * C_ + cb + reg) * T_ + t] = v;
            const unsigned short hb = bf16_rne(v);
            const float hf = __builtin_bit_cast(float, (unsigned int)hb << 16);
            const unsigned short lb = bf16_rne(v - hf);
            E[tl * ELD + mm * 16 + quad * 4 + reg] =
                ((unsigned int)hb << 16) | (unsigned int)lb;
          }
        }
      }
      __syncthreads();
      // coalesced store phase: thread = t-row, 32 consecutive co (64 B/plane)
      {
        const int row = tid;
        uint32_t u[32];
#pragma unroll
        for (int j = 0; j < 32; ++j) u[j] = E[row * ELD + j];
        u16x8 hq[4], lq[4];
#pragma unroll
        for (int g = 0; g < 4; ++g)
#pragma unroll
          for (int j = 0; j < 8; ++j) {
            hq[g][j] = (unsigned short)(u[g * 8 + j] >> 16);
            lq[g][j] = (unsigned short)(u[g * 8 + j] & 0xFFFFu);
          }
        const size_t poff = ((size_t)b * T_ + t0 + row) * C_ + co0 + mb * 32;
#pragma unroll
        for (int g = 0; g < 4; ++g) {
          *(u16x8*)(Ohi + poff + g * 8) = hq[g];
          *(u16x8*)(Olo + poff + g * 8) = lq[g];
        }
      }
    }
  } else {
    // fp32-only epilogue (coalesced along t)
#pragma unroll
    for (int m = 0; m < 8; ++m) {
      const int cb = co0 + m * 16 + quad * 4;
      float bs[4], av[4], ibv[4];
#pragma unroll
      for (int reg = 0; reg < 4; ++reg) {
        bs[reg] = bias[cb + reg];
        if (SNAKE) { av[reg] = aexp[cb + reg]; ibv[reg] = invb[cb + reg]; }
      }
#pragma unroll
      for (int n = 0; n < 4; ++n) {
        const int t = t0 + wv * 64 + n * 16 + l15;
#pragma unroll
        for (int reg = 0; reg < 4; ++reg) {
          float v = sw * acc[m][n][reg] + bs[reg];
          if (SNAKE) {
            const float sn = __sinf(av[reg] * v);
            v = v + ibv[reg] * sn * sn;
          } else {
            v = v + res[((size_t)b * C_ + cb + reg) * T_ + t];
          }
          Y[((size_t)b * C_ + cb + reg) * T_ + t] = v;
        }
      }
    }
  }
}

// ------------------------------- launch -------------------------------------
extern "C" void kernel_launch(void* const* d_in, const int* in_sizes, int n_in,
                              void* d_out, int out_size, void* d_ws, size_t ws_size,
                              hipStream_t stream) {
  (void)in_sizes; (void)n_in; (void)out_size; (void)ws_size;
  const float* x = (const float*)d_in[0];
  const float* w1 = (const float*)d_in[1];
  const float* b1 = (const float*)d_in[2];
  const float* al = (const float*)d_in[3];
  const float* be = (const float*)d_in[4];
  const float* w2 = (const float*)d_in[5];
  const float* b2 = (const float*)d_in[6];
  float* out = (float*)d_out;
  char* wsb = (char*)d_ws;

  float* part = (float*)(wsb + OFF_PART);
  float* svec = (float*)(wsb + OFF_S);
  float* ae = (float*)(wsb + OFF_AE);
  float* ib = (float*)(wsb + OFF_IB);
  unsigned short* wq1 = (unsigned short*)(wsb + OFF_WQ1);
  unsigned short* wq2 = (unsigned short*)(wsb + OFF_WQ2);
  unsigned short* Phi = (unsigned short*)(wsb + OFF_PHI);
  unsigned short* Plo = (unsigned short*)(wsb + OFF_PLO);
  unsigned short* Qhi = (unsigned short*)(wsb + OFF_QHI);
  unsigned short* Qlo = (unsigned short*)(wsb + OFF_QLO);

  absmean_partial<<<dim3(96, 6), 256, 0, stream>>>(w1, w2, part);
  absmean_final<<<6, 128, 0, stream>>>(part, svec);
  quantize_kernel<<<(3 * WELEM) / 256, 256, 0, stream>>>(w1, wq1, svec, 0);
  quantize_kernel<<<(3 * WELEM) / 256, 256, 0, stream>>>(w2, wq2, svec, 3);
  snake_params_kernel<<<6, 256, 0, stream>>>(al, be, ae, ib);

  const dim3 tgrid(T_ / 64, C_ / 64, B_);
  const dim3 cgrid(T_ / 256, C_ / 128, B_);

  transpose_split<<<tgrid, 256, 0, stream>>>(x, Phi, Plo);

  // stage 0 (dil=1): conv1 P->Q planes; conv2 Q->out fp32 + P planes
  conv_mfma<1, true, true, false><<<cgrid, 256, 0, stream>>>(
      Phi, Plo, wq1 + 0 * (size_t)WELEM, svec + 0, b1 + 0, ae + 0, ib + 0,
      nullptr, nullptr, Qhi, Qlo);
  conv_mfma<1, false, true, true><<<cgrid, 256, 0, stream>>>(
      Qhi, Qlo, wq2 + 0 * (size_t)WELEM, svec + 3, b2 + 0, nullptr, nullptr,
      x, out, Phi, Plo);

  // stage 1 (dil=3)
  conv_mfma<3, true, true, false><<<cgrid, 256, 0, stream>>>(
      Phi, Plo, wq1 + 1 * (size_t)WELEM, svec + 1, b1 + C_, ae + C_, ib + C_,
      nullptr, nullptr, Qhi, Qlo);
  conv_mfma<1, false, true, true><<<cgrid, 256, 0, stream>>>(
      Qhi, Qlo, wq2 + 1 * (size_t)WELEM, svec + 4, b2 + C_, nullptr, nullptr,
      out, out, Phi, Plo);

  // stage 2 (dil=5): final conv2 writes fp32 only
  conv_mfma<5, true, true, false><<<cgrid, 256, 0, stream>>>(
      Phi, Plo, wq1 + 2 * (size_t)WELEM, svec + 2, b1 + 2 * C_, ae + 2 * C_,
      ib + 2 * C_, nullptr, nullptr, Qhi, Qlo);
  conv_mfma<1, false, false, true><<<cgrid, 256, 0, stream>>>(
      Qhi, Qlo, wq2 + 2 * (size_t)WELEM, svec + 5, b2 + 2 * C_, nullptr, nullptr,
      out, out, nullptr, nullptr);
}

// Round 8
// 751.136 us; speedup vs baseline: 4.1073x; 1.1214x over previous
//
#include <hip/hip_runtime.h>
#include <math.h>
#include <stdint.h>

// ---------------------------------------------------------------------------
// BitResidualBlock via bf16-split MFMA.
// R8: async K-loop — X staged with __builtin_amdgcn_global_load_lds (16B) into
// a double-buffered, plane-interleaved, XOR-swizzled LDS layout; ONE barrier
// per cc. Staging for cc+1 is in flight during cc's MFMA body (m97 pattern).
// Row r (128 B) = 8 x 16B chunks; chunk c stored at c' = c ^ (r&7) ->
// b128 fragment reads are 2-way (free); DMA windows are 1024 B contiguous.
// OOB halo lanes read from a zeroed ws region. Epilogue as R7 (all acc
// indices compile-time -- NEVER runtime-index a register array).
// ---------------------------------------------------------------------------

constexpr int B_ = 8, C_ = 512, T_ = 4096, K_ = 3;
constexpr int WELEM = C_ * C_ * K_;  // 786432 per tensor

typedef __bf16 bf16x8 __attribute__((ext_vector_type(8)));
typedef float f32x4 __attribute__((ext_vector_type(4)));
typedef unsigned short u16x8 __attribute__((ext_vector_type(8)));

// ws byte offsets
constexpr size_t OFF_PART = 0;
constexpr size_t OFF_S = 4096;
constexpr size_t OFF_AE = 8192;
constexpr size_t OFF_IB = 16384;
constexpr size_t OFF_WQ1 = 32768;  // ushort[3*WELEM], frag-swizzled
constexpr size_t OFF_WQ2 = OFF_WQ1 + (size_t)3 * WELEM * 2;
constexpr size_t NBCT = (size_t)B_ * C_ * T_;
constexpr size_t OFF_PHI = OFF_WQ2 + (size_t)3 * WELEM * 2;  // bf16 planes
constexpr size_t OFF_PLO = OFF_PHI + NBCT * 2;
constexpr size_t OFF_QHI = OFF_PLO + NBCT * 2;
constexpr size_t OFF_QLO = OFF_QHI + NBCT * 2;
constexpr size_t OFF_ZERO = OFF_QLO + NBCT * 2;  // 4 KB zeroed region

__device__ inline unsigned short bf16_rne(float v) {
  unsigned int u = __builtin_bit_cast(unsigned int, v);
  unsigned int r = u + 0x7FFFu + ((u >> 16) & 1u);
  return (unsigned short)(r >> 16);
}

// --------------------------- absmean (deterministic) ------------------------
__global__ __launch_bounds__(256)
void absmean_partial(const float* __restrict__ w1, const float* __restrict__ w2,
                     float* __restrict__ part) {
  __shared__ float red[256];
  const int t = blockIdx.y;
  const float* src = (t < 3) ? (w1 + (size_t)t * WELEM) : (w2 + (size_t)(t - 3) * WELEM);
  const int base = blockIdx.x * (256 * 32);
  float v = 0.f;
#pragma unroll
  for (int j = 0; j < 32; ++j) v += fabsf(src[base + j * 256 + threadIdx.x]);
  red[threadIdx.x] = v;
  __syncthreads();
  for (int s = 128; s > 0; s >>= 1) {
    if (threadIdx.x < (unsigned)s) red[threadIdx.x] += red[threadIdx.x + s];
    __syncthreads();
  }
  if (threadIdx.x == 0) part[t * 96 + blockIdx.x] = red[0];
}

__global__ __launch_bounds__(128)
void absmean_final(const float* __restrict__ part, float* __restrict__ svec) {
  __shared__ float red[128];
  const int t = blockIdx.x;
  red[threadIdx.x] = (threadIdx.x < 96) ? part[t * 96 + threadIdx.x] : 0.f;
  __syncthreads();
  for (int s = 64; s > 0; s >>= 1) {
    if (threadIdx.x < (unsigned)s) red[threadIdx.x] += red[threadIdx.x + s];
    __syncthreads();
  }
  if (threadIdx.x == 0) svec[t] = red[0] / (float)WELEM;
}

// --------------------------- quantize -> ternary bf16, frag-swizzled --------
// dst layout: idx = (((st*16 + cc)*3 + tap)*32 + cot)*512 + lane*8 + j
//   where co = cot*16 + (lane&15), ci = cc*32 + (lane>>4)*8 + j.
__global__ __launch_bounds__(256)
void quantize_kernel(const float* __restrict__ src, unsigned short* __restrict__ dst,
                     const float* __restrict__ svec, int sbase) {
  const int idx = blockIdx.x * 256 + threadIdx.x;  // exact grid over 3*WELEM
  const int j = idx & 7;
  const int lane = (idx >> 3) & 63;
  const int cot = (idx >> 9) & 31;
  const int rest = idx >> 14;
  const int tap = rest % 3;
  const int rest2 = rest / 3;
  const int cc = rest2 & 15;
  const int st = rest2 >> 4;
  const int co = cot * 16 + (lane & 15);
  const int ci = cc * 32 + (lane >> 4) * 8 + j;
  const float s = svec[sbase + st];
  const float w = src[(((size_t)st * C_ + co) * C_ + ci) * K_ + tap];
  float q = rintf(w / (s + 1e-5f));
  q = fminf(1.f, fmaxf(-1.f, q));
  dst[idx] = (unsigned short)(__builtin_bit_cast(unsigned int, q) >> 16);
}

__global__ __launch_bounds__(256)
void snake_params_kernel(const float* __restrict__ al, const float* __restrict__ be,
                         float* __restrict__ ae, float* __restrict__ ib,
                         float* __restrict__ zr) {
  const int idx = blockIdx.x * 256 + threadIdx.x;
  if (idx < 3 * C_) {
    ae[idx] = expf(al[idx]);
    ib[idx] = 1.f / (expf(be[idx]) + 1e-9f);
  }
  if (idx < 1024) zr[idx] = 0.f;  // 4 KB zeros for OOB halo DMA
}

// --------------------------- transpose + hi/lo split (used once, for x) -----
__global__ __launch_bounds__(256)
void transpose_split(const float* __restrict__ X, unsigned short* __restrict__ Hi,
                     unsigned short* __restrict__ Lo) {
  __shared__ float tile[64][68];
  const int b = blockIdx.z;
  const int c0 = blockIdx.y * 64;
  const int t0 = blockIdx.x * 64;
  const int tid = threadIdx.x;
  {
    const int cl = tid >> 2, tg = tid & 3;
    const float* src = X + ((size_t)b * C_ + c0 + cl) * T_ + t0 + tg * 16;
    float4 v0 = *(const float4*)(src);
    float4 v1 = *(const float4*)(src + 4);
    float4 v2 = *(const float4*)(src + 8);
    float4 v3 = *(const float4*)(src + 12);
    float* d = &tile[cl][tg * 16];
    *(float4*)(d) = v0; *(float4*)(d + 4) = v1;
    *(float4*)(d + 8) = v2; *(float4*)(d + 12) = v3;
  }
  __syncthreads();
  {
    const int tl = tid >> 2, cg = tid & 3;
    u16x8 h0, h1, l0, l1;
#pragma unroll
    for (int j = 0; j < 16; ++j) {
      const float v = tile[cg * 16 + j][tl];
      const unsigned short hb = bf16_rne(v);
      const float hf = __builtin_bit_cast(float, (unsigned int)hb << 16);
      const unsigned short lb = bf16_rne(v - hf);
      if (j < 8) { h0[j] = hb; l0[j] = lb; }
      else       { h1[j - 8] = hb; l1[j - 8] = lb; }
    }
    const size_t off = ((size_t)b * T_ + t0 + tl) * C_ + c0 + cg * 16;
    *(u16x8*)(Hi + off) = h0; *(u16x8*)(Hi + off + 8) = h1;
    *(u16x8*)(Lo + off) = l0; *(u16x8*)(Lo + off + 8) = l1;
  }
}

// ------------------------------- MFMA conv ----------------------------------
// Block: 128 co x 256 t, 256 threads (4 waves), wave = 128 co x 64 t.
// Async double-buffered staging via global_load_lds, one barrier per cc.
template <int DIL, bool SNAKE, bool PLANES, bool WF32>
__global__ __launch_bounds__(256, 2)
void conv_mfma(const unsigned short* __restrict__ Xhi,  // [b][T][C] bf16 bits
               const unsigned short* __restrict__ Xlo,
               const unsigned short* __restrict__ Wq,   // frag-swizzled
               unsigned int zoff,                       // bytes: Xhi -> zeros
               const float* __restrict__ svec,
               const float* __restrict__ bias, const float* __restrict__ aexp,
               const float* __restrict__ invb,
               const float* __restrict__ res,           // fp32 [b][co][t]
               float* __restrict__ Y,                   // fp32 [b][co][t]
               unsigned short* __restrict__ Ohi,        // [b][T][C] planes
               unsigned short* __restrict__ Olo) {
  constexpr int TT = 256;
  constexpr int R = TT + 2 * DIL;
  constexpr int R8 = (R + 7) & ~7;      // rows padded to DMA window multiple
  constexpr int W8 = R8 / 8;            // 1024 B DMA windows per buffer
  constexpr int NW = (W8 + 3) / 4;      // windows per wave (ceil)
  __shared__ unsigned short Xs[2][R8 * 64];  // row = 128 B (both planes, swizzled)

  const int b = blockIdx.z;
  const int co0 = blockIdx.y * 128;
  const int cob = blockIdx.y * 8;
  const int t0 = blockIdx.x * TT;
  const int tid = threadIdx.x;
  const int lane = tid & 63;
  const int wv = tid >> 6;
  const int l15 = lane & 15;
  const int quad = lane >> 4;

  f32x4 acc[8][4] = {};

  const size_t xbase = (size_t)b * T_ * C_;
  const unsigned int plo_delta = (unsigned int)(NBCT * 2);  // bytes Xlo - Xhi
  const char* xh8 = (const char*)Xhi;

  // Per-lane DMA source byte offsets (from Xhi), one per window handled.
  // LDS slot for lane i in window wnd: row rl = wnd*8 + (i>>3), chunk c' = i&7.
  // Stored content: c = c' ^ (rl&7) -> plane p = c>>2, ci-group g = c&3.
  unsigned int offs[NW];
#pragma unroll
  for (int j = 0; j < NW; ++j) {
    const int wnd = wv + j * 4;
    const int rl = wnd * 8 + (lane >> 3);
    const int cpr = (lane & 7) ^ (rl & 7);
    const int p = cpr >> 2, g = cpr & 3;
    const int t = t0 - DIL + rl;
    unsigned int o;
    if (wnd < W8 && (unsigned)t < (unsigned)T_)
      o = (p ? plo_delta : 0u) + (unsigned int)((xbase + (size_t)t * C_ + g * 8) * 2);
    else
      o = zoff + (unsigned int)(g * 16);  // zeros region (advances by cc*64 <= 1 KB)
    offs[j] = o;
  }

  auto stage = [&](int cc, int buf) {
#pragma unroll
    for (int j = 0; j < NW; ++j) {
      const int wnd = wv + j * 4;
      if (wnd < W8) {
        const char* gp = xh8 + offs[j] + cc * 64;
        __builtin_amdgcn_global_load_lds(
            (const __attribute__((address_space(1))) unsigned int*)gp,
            (__attribute__((address_space(3))) unsigned int*)&Xs[buf][wnd * 512],
            16, 0, 0);
      }
    }
  };

  stage(0, 0);
  __syncthreads();

#pragma unroll 1
  for (int cc = 0; cc < C_ / 32; ++cc) {
    const int cur = cc & 1;

    // tap 0 A-frags FIRST: their vmcnt wait retires only these (older than
    // the staging issued below), so the new staging stays in flight.
    bf16x8 a0[8];
    {
      const unsigned short* wb =
          Wq + (((size_t)cc * K_ + 0) * 32 + cob) * 512 + (size_t)lane * 8;
#pragma unroll
      for (int m = 0; m < 8; ++m)
        a0[m] = __builtin_bit_cast(bf16x8, *(const u16x8*)(wb + m * 512));
    }

    if (cc < C_ / 32 - 1) stage(cc + 1, 1 - cur);  // async, drains at barrier

#pragma unroll
    for (int n = 0; n < 4; ++n) {
      const int r = wv * 64 + n * 16 + l15;  // tap 0
      const int rw = (r & 7) * 8;
      const bf16x8 bh =
          __builtin_bit_cast(bf16x8, *(const u16x8*)&Xs[cur][r * 64 + ((quad * 8) ^ rw)]);
      const bf16x8 bl =
          __builtin_bit_cast(bf16x8, *(const u16x8*)&Xs[cur][r * 64 + ((quad * 8 + 32) ^ rw)]);
#pragma unroll
      for (int m = 0; m < 8; ++m) {
        acc[m][n] = __builtin_amdgcn_mfma_f32_16x16x32_bf16(a0[m], bh, acc[m][n], 0, 0, 0);
        acc[m][n] = __builtin_amdgcn_mfma_f32_16x16x32_bf16(a0[m], bl, acc[m][n], 0, 0, 0);
      }
    }

#pragma unroll
    for (int tap = 1; tap < K_; ++tap) {
      const unsigned short* wb =
          Wq + (((size_t)cc * K_ + tap) * 32 + cob) * 512 + (size_t)lane * 8;
      bf16x8 a[8];
#pragma unroll
      for (int m = 0; m < 8; ++m)
        a[m] = __builtin_bit_cast(bf16x8, *(const u16x8*)(wb + m * 512));
#pragma unroll
      for (int n = 0; n < 4; ++n) {
        const int r = wv * 64 + n * 16 + l15 + tap * DIL;
        const int rw = (r & 7) * 8;
        const bf16x8 bh =
            __builtin_bit_cast(bf16x8, *(const u16x8*)&Xs[cur][r * 64 + ((quad * 8) ^ rw)]);
        const bf16x8 bl =
            __builtin_bit_cast(bf16x8, *(const u16x8*)&Xs[cur][r * 64 + ((quad * 8 + 32) ^ rw)]);
#pragma unroll
        for (int m = 0; m < 8; ++m) {
          acc[m][n] = __builtin_amdgcn_mfma_f32_16x16x32_bf16(a[m], bh, acc[m][n], 0, 0, 0);
          acc[m][n] = __builtin_amdgcn_mfma_f32_16x16x32_bf16(a[m], bl, acc[m][n], 0, 0, 0);
        }
      }
    }
    __syncthreads();  // drains staging (had the whole body to land) + LDS RAW
  }

  // ---- fused epilogue ----
  const float sw = *svec;

  if (PLANES) {
    // Round-trip through LDS so plane stores are 64B-contiguous per thread.
    uint32_t* E = (uint32_t*)&Xs[0][0];  // 256 x 33 u32 = 33792 B <= R8*128
    constexpr int ELD = 33;
#pragma unroll
    for (int mb = 0; mb < 4; ++mb) {  // chunks of 2 m-tiles = 32 co
      __syncthreads();
#pragma unroll
      for (int mm = 0; mm < 2; ++mm) {
        const int m = mb * 2 + mm;
        const int cb = co0 + m * 16 + quad * 4;
        float bs[4], av[4], ibv[4];
#pragma unroll
        for (int reg = 0; reg < 4; ++reg) {
          bs[reg] = bias[cb + reg];
          if (SNAKE) { av[reg] = aexp[cb + reg]; ibv[reg] = invb[cb + reg]; }
        }
#pragma unroll
        for (int n = 0; n < 4; ++n) {
          const int tl = wv * 64 + n * 16 + l15;
          const int t = t0 + tl;
#pragma unroll
          for (int reg = 0; reg < 4; ++reg) {
            float v = sw * acc[m][n][reg] + bs[reg];
            if (SNAKE) {
              const float sn = __sinf(av[reg] * v);
              v = v + ibv[reg] * sn * sn;
            } else {
              v = v + res[((size_t)b * C_ + cb + reg) * T_ + t];
            }
            if (WF32) Y[((size_t)b * C_ + cb + reg) * T_ + t] = v;
            const unsigned short hb = bf16_rne(v);
            const float hf = __builtin_bit_cast(float, (unsigned int)hb << 16);
            const unsigned short lb = bf16_rne(v - hf);
            E[tl * ELD + mm * 16 + quad * 4 + reg] =
                ((unsigned int)hb << 16) | (unsigned int)lb;
          }
        }
      }
      __syncthreads();
      {
        const int row = tid;
        uint32_t u[32];
#pragma unroll
        for (int j = 0; j < 32; ++j) u[j] = E[row * ELD + j];
        u16x8 hq[4], lq[4];
#pragma unroll
        for (int g = 0; g < 4; ++g)
#pragma unroll
          for (int j = 0; j < 8; ++j) {
            hq[g][j] = (unsigned short)(u[g * 8 + j] >> 16);
            lq[g][j] = (unsigned short)(u[g * 8 + j] & 0xFFFFu);
          }
        const size_t poff = ((size_t)b * T_ + t0 + row) * C_ + co0 + mb * 32;
#pragma unroll
        for (int g = 0; g < 4; ++g) {
          *(u16x8*)(Ohi + poff + g * 8) = hq[g];
          *(u16x8*)(Olo + poff + g * 8) = lq[g];
        }
      }
    }
  } else {
#pragma unroll
    for (int m = 0; m < 8; ++m) {
      const int cb = co0 + m * 16 + quad * 4;
      float bs[4], av[4], ibv[4];
#pragma unroll
      for (int reg = 0; reg < 4; ++reg) {
        bs[reg] = bias[cb + reg];
        if (SNAKE) { av[reg] = aexp[cb + reg]; ibv[reg] = invb[cb + reg]; }
      }
#pragma unroll
      for (int n = 0; n < 4; ++n) {
        const int t = t0 + wv * 64 + n * 16 + l15;
#pragma unroll
        for (int reg = 0; reg < 4; ++reg) {
          float v = sw * acc[m][n][reg] + bs[reg];
          if (SNAKE) {
            const float sn = __sinf(av[reg] * v);
            v = v + ibv[reg] * sn * sn;
          } else {
            v = v + res[((size_t)b * C_ + cb + reg) * T_ + t];
          }
          Y[((size_t)b * C_ + cb + reg) * T_ + t] = v;
        }
      }
    }
  }
}

// ------------------------------- launch -------------------------------------
extern "C" void kernel_launch(void* const* d_in, const int* in_sizes, int n_in,
                              void* d_out, int out_size, void* d_ws, size_t ws_size,
                              hipStream_t stream) {
  (void)in_sizes; (void)n_in; (void)out_size; (void)ws_size;
  const float* x = (const float*)d_in[0];
  const float* w1 = (const float*)d_in[1];
  const float* b1 = (const float*)d_in[2];
  const float* al = (const float*)d_in[3];
  const float* be = (const float*)d_in[4];
  const float* w2 = (const float*)d_in[5];
  const float* b2 = (const float*)d_in[6];
  float* out = (float*)d_out;
  char* wsb = (char*)d_ws;

  float* part = (float*)(wsb + OFF_PART);
  float* svec = (float*)(wsb + OFF_S);
  float* ae = (float*)(wsb + OFF_AE);
  float* ib = (float*)(wsb + OFF_IB);
  unsigned short* wq1 = (unsigned short*)(wsb + OFF_WQ1);
  unsigned short* wq2 = (unsigned short*)(wsb + OFF_WQ2);
  unsigned short* Phi = (unsigned short*)(wsb + OFF_PHI);
  unsigned short* Plo = (unsigned short*)(wsb + OFF_PLO);
  unsigned short* Qhi = (unsigned short*)(wsb + OFF_QHI);
  unsigned short* Qlo = (unsigned short*)(wsb + OFF_QLO);
  float* zr = (float*)(wsb + OFF_ZERO);

  const unsigned int zoffP = (unsigned int)(OFF_ZERO - OFF_PHI);
  const unsigned int zoffQ = (unsigned int)(OFF_ZERO - OFF_QHI);

  absmean_partial<<<dim3(96, 6), 256, 0, stream>>>(w1, w2, part);
  absmean_final<<<6, 128, 0, stream>>>(part, svec);
  quantize_kernel<<<(3 * WELEM) / 256, 256, 0, stream>>>(w1, wq1, svec, 0);
  quantize_kernel<<<(3 * WELEM) / 256, 256, 0, stream>>>(w2, wq2, svec, 3);
  snake_params_kernel<<<6, 256, 0, stream>>>(al, be, ae, ib, zr);

  const dim3 tgrid(T_ / 64, C_ / 64, B_);
  const dim3 cgrid(T_ / 256, C_ / 128, B_);

  transpose_split<<<tgrid, 256, 0, stream>>>(x, Phi, Plo);

  // stage 0 (dil=1): conv1 P->Q planes; conv2 Q->out fp32 + P planes
  conv_mfma<1, true, true, false><<<cgrid, 256, 0, stream>>>(
      Phi, Plo, wq1 + 0 * (size_t)WELEM, zoffP, svec + 0, b1 + 0, ae + 0, ib + 0,
      nullptr, nullptr, Qhi, Qlo);
  conv_mfma<1, false, true, true><<<cgrid, 256, 0, stream>>>(
      Qhi, Qlo, wq2 + 0 * (size_t)WELEM, zoffQ, svec + 3, b2 + 0, nullptr, nullptr,
      x, out, Phi, Plo);

  // stage 1 (dil=3)
  conv_mfma<3, true, true, false><<<cgrid, 256, 0, stream>>>(
      Phi, Plo, wq1 + 1 * (size_t)WELEM, zoffP, svec + 1, b1 + C_, ae + C_, ib + C_,
      nullptr, nullptr, Qhi, Qlo);
  conv_mfma<1, false, true, true><<<cgrid, 256, 0, stream>>>(
      Qhi, Qlo, wq2 + 1 * (size_t)WELEM, zoffQ, svec + 4, b2 + C_, nullptr, nullptr,
      out, out, Phi, Plo);

  // stage 2 (dil=5): final conv2 writes fp32 only
  conv_mfma<5, true, true, false><<<cgrid, 256, 0, stream>>>(
      Phi, Plo, wq1 + 2 * (size_t)WELEM, zoffP, svec + 2, b1 + 2 * C_, ae + 2 * C_,
      ib + 2 * C_, nullptr, nullptr, Qhi, Qlo);
  conv_mfma<1, false, false, true><<<cgrid, 256, 0, stream>>>(
      Qhi, Qlo, wq2 + 2 * (size_t)WELEM, zoffQ, svec + 5, b2 + 2 * C_, nullptr, nullptr,
      out, out, nullptr, nullptr);
}